// Round 17
// baseline (176.376 us; speedup 1.0000x reference)
//
#include <hip/hip_runtime.h>
#include <hip/hip_bf16.h>
#include <math.h>

#define BB 2
#define SS 2048
#define EE 768
#define HH 12
#define DD 64
#define MM (BB*SS)          // 4096 rows
#define BH (BB*HH)          // 24 heads total
#define NM ((size_t)MM*EE)  // 3145728 elements per [B,S,E] buffer
#define WSZ ((size_t)EE*EE) // 589824 weight elements
#define BHS ((size_t)BH*SS) // 49152

typedef __attribute__((ext_vector_type(8))) short bf16x8;   // 8 bf16 in 4 VGPR
typedef __attribute__((ext_vector_type(4))) float f32x4;    // MFMA C/D frag

// ---------------- helpers ----------------
__device__ __forceinline__ float wave_sum64(float v) {
#pragma unroll
  for (int off = 32; off > 0; off >>= 1) v += __shfl_down(v, off, 64);
  return v;
}

__device__ __forceinline__ unsigned int pack_bf2(float x, float y) {
  unsigned int a = __float_as_uint(x), b = __float_as_uint(y);
  a += 0x7fffu + ((a >> 16) & 1u);
  b += 0x7fffu + ((b >> 16) & 1u);
  return (a >> 16) | (b & 0xffff0000u);
}
__device__ __forceinline__ unsigned int cvtpk_bf2(float x, float y) {
  __hip_bfloat162 h = __float22bfloat162_rn(make_float2(x, y));
  union { __hip_bfloat162 h2; unsigned int u; } c; c.h2 = h;
  return c.u;
}
__device__ __forceinline__ ushort bf16_1(float x) {
  unsigned int u = __float_as_uint(x);
  u += 0x7fffu + ((u >> 16) & 1u);
  return (ushort)(u >> 16);
}

// -acos(x)^2 = w * p(w), w = (1-x)/2.  5-op natural-domain poly (asin^2 series,
// tail minimax-bumped: -4(1 + w/3 + 8w^2/45 + 4w^3/35 + 0.154w^4)).
// score = __expf(w*p + lcw), lcw = -0.5*ln(colsum).
__device__ __forceinline__ void score_wp(float cosv, float& w, float& p) {
  w = fmaxf(fmaf(cosv, -0.5f, 0.5f), 0.0f);
  p = fmaf(w, -0.616000f, -0.4571429f);
  p = fmaf(w, p, -0.7111111f);
  p = fmaf(w, p, -1.3333333f);
  p = fmaf(w, p, -4.0f);
}

// ---------------- 1. row l2-norm over E -> bf16 ----------------
__global__ __launch_bounds__(256) void k_rownorm(const float* __restrict__ x,
                                                 ushort* __restrict__ o) {
  int row = blockIdx.x;
  int tid = threadIdx.x;
  const float* xr = x + (size_t)row * EE;
  ushort* orow = o + (size_t)row * EE;
  float v0 = xr[tid], v1 = xr[tid + 256], v2 = xr[tid + 512];
  float ss = v0 * v0 + v1 * v1 + v2 * v2;
  ss = wave_sum64(ss);
  __shared__ float red[4];
  if ((tid & 63) == 0) red[tid >> 6] = ss;
  __syncthreads();
  float tot = red[0] + red[1] + red[2] + red[3];
  float sc = 1.0f / fmaxf(sqrtf(tot), 1e-12f);
  orow[tid]       = bf16_1(v0 * sc);
  orow[tid + 256] = bf16_1(v1 * sc);
  orow[tid + 512] = bf16_1(v2 * sc);
}

// ---------------- 2. weight transpose -> bf16 Wt[n][k] ----------------
__global__ __launch_bounds__(256) void k_transp(const float* __restrict__ Wq,
                                                const float* __restrict__ Wk,
                                                const float* __restrict__ Wv,
                                                const float* __restrict__ Wo,
                                                ushort* __restrict__ wt) {
  int z = blockIdx.z;
  const float* W = (z == 0) ? Wq : (z == 1) ? Wk : (z == 2) ? Wv : Wo;
  ushort* dst = wt + (size_t)z * WSZ;
  int n0 = blockIdx.x * 64, k0 = blockIdx.y * 64;
  __shared__ float t[64][65];
  int tid = threadIdx.x;
  int r4 = tid >> 4, c4 = (tid & 15) * 4;
#pragma unroll
  for (int i = 0; i < 4; ++i) {
    float4 v = *(const float4*)(W + (size_t)(k0 + i * 16 + r4) * EE + n0 + c4);
    t[i * 16 + r4][c4 + 0] = v.x; t[i * 16 + r4][c4 + 1] = v.y;
    t[i * 16 + r4][c4 + 2] = v.z; t[i * 16 + r4][c4 + 3] = v.w;
  }
  __syncthreads();
  int nr = tid >> 3, c8 = (tid & 7) * 8;
#pragma unroll
  for (int j = 0; j < 2; ++j) {
    int n = nr + j * 32;
    unsigned int p[4];
#pragma unroll
    for (int e = 0; e < 4; ++e)
      p[e] = pack_bf2(t[c8 + 2 * e][n], t[c8 + 2 * e + 1][n]);
    uint4 pv; pv.x = p[0]; pv.y = p[1]; pv.z = p[2]; pv.w = p[3];
    *(uint4*)(dst + (size_t)(n0 + n) * EE + k0 + c8) = pv;
  }
}

// ---------------- 3. QKV GEMM (bf16 MFMA, 2-phase LDS double-buffer) ----
__global__ __launch_bounds__(256) void k_gemm_qkv_mfma(
    const ushort* __restrict__ hsb,
    const ushort* __restrict__ wt,
    const float* __restrict__ b0, const float* __restrict__ b1, const float* __restrict__ b2,
    ushort* __restrict__ qb, ushort* __restrict__ kb, ushort* __restrict__ vtb) {
  int bid = blockIdx.x;
  int xcd = bid & 7; int rr = bid >> 3;
  int n_idx = rr % 12; int m_in = (rr / 12) & 7; int z = rr / 96;
  int n0 = n_idx * 64; int m0 = (xcd * 8 + m_in) * 64;
  const ushort* W = wt + (size_t)z * WSZ;
  const float* bias = (z == 0) ? b0 : (z == 1) ? b1 : b2;
  __shared__ ushort As[2][64][72];
  __shared__ ushort Bs[2][64][72];
  int tid = threadIdx.x, w = tid >> 6, l = tid & 63, li = l & 15, g = l >> 4;
  int srow = tid >> 3, scol = (tid & 7) * 8;
  const ushort* Aba = hsb + (size_t)(m0 + srow) * EE + scol;
  const ushort* Wba = W + (size_t)(n0 + srow) * EE + scol;
  f32x4 acc[4];
#pragma unroll
  for (int u = 0; u < 4; ++u) acc[u] = (f32x4){0.f, 0.f, 0.f, 0.f};
  bf16x8 pA0 = *(const bf16x8*)(Aba);
  bf16x8 pA1 = *(const bf16x8*)(Aba + 32 * EE);
  bf16x8 pW0 = *(const bf16x8*)(Wba);
  bf16x8 pW1 = *(const bf16x8*)(Wba + 32 * EE);
  *(bf16x8*)&As[0][srow][scol] = pA0;
  *(bf16x8*)&As[0][srow + 32][scol] = pA1;
  *(bf16x8*)&Bs[0][srow][scol] = pW0;
  *(bf16x8*)&Bs[0][srow + 32][scol] = pW1;
  __syncthreads();
#pragma unroll
  for (int kt = 0; kt < 12; ++kt) {
    int cur = kt & 1;
    if (kt < 11) {
      int k0 = (kt + 1) * 64;
      pA0 = *(const bf16x8*)(Aba + k0);
      pA1 = *(const bf16x8*)(Aba + 32 * EE + k0);
      pW0 = *(const bf16x8*)(Wba + k0);
      pW1 = *(const bf16x8*)(Wba + 32 * EE + k0);
    }
    bf16x8 a0 = *(const bf16x8*)&As[cur][w * 16 + li][8 * g];
    bf16x8 a1 = *(const bf16x8*)&As[cur][w * 16 + li][32 + 8 * g];
#pragma unroll
    for (int u = 0; u < 4; ++u) {
      bf16x8 bb0 = *(const bf16x8*)&Bs[cur][u * 16 + li][8 * g];
      bf16x8 bb1 = *(const bf16x8*)&Bs[cur][u * 16 + li][32 + 8 * g];
      acc[u] = __builtin_amdgcn_mfma_f32_16x16x32_bf16(a0, bb0, acc[u], 0, 0, 0);
      acc[u] = __builtin_amdgcn_mfma_f32_16x16x32_bf16(a1, bb1, acc[u], 0, 0, 0);
    }
    __syncthreads();
    if (kt < 11) {
      int nxt = cur ^ 1;
      *(bf16x8*)&As[nxt][srow][scol] = pA0;
      *(bf16x8*)&As[nxt][srow + 32][scol] = pA1;
      *(bf16x8*)&Bs[nxt][srow][scol] = pW0;
      *(bf16x8*)&Bs[nxt][srow + 32][scol] = pW1;
      __syncthreads();
    }
  }
  float val[4][4];
#pragma unroll
  for (int u = 0; u < 4; ++u) {
    float bia = bias[n0 + u * 16 + li];
#pragma unroll
    for (int r = 0; r < 4; ++r) val[u][r] = acc[u][r] + bia;
  }
  if (z < 2) {
#pragma unroll
    for (int r = 0; r < 4; ++r) {
      float ss = val[0][r] * val[0][r] + val[1][r] * val[1][r] +
                 val[2][r] * val[2][r] + val[3][r] * val[3][r];
      ss += __shfl_xor(ss, 1, 64);
      ss += __shfl_xor(ss, 2, 64);
      ss += __shfl_xor(ss, 4, 64);
      ss += __shfl_xor(ss, 8, 64);
      float sc = rsqrtf(fmaxf(ss, 1e-24f));
#pragma unroll
      for (int u = 0; u < 4; ++u) val[u][r] *= sc;
    }
  }
  ushort (*tile)[72] = As[0];
#pragma unroll
  for (int u = 0; u < 4; ++u)
#pragma unroll
    for (int r = 0; r < 4; ++r) {
      int ml = w * 16 + 4 * g + r, d = u * 16 + li;
      if (z < 2) tile[ml][d] = bf16_1(val[u][r]);
      else       tile[d][ml] = bf16_1(val[u][r]);
    }
  __syncthreads();
  int h = n_idx, b_ = m0 >> 11, s0 = m0 & 2047;
  int bh = b_ * HH + h;
  int row = tid >> 2, c16 = (tid & 3) * 16;
  bf16x8 o0 = *(const bf16x8*)&tile[row][c16];
  bf16x8 o1 = *(const bf16x8*)&tile[row][c16 + 8];
  ushort* dst;
  if (z < 2) {
    dst = (z ? kb : qb) + ((size_t)bh * SS + s0 + row) * 64 + c16;
  } else {
    dst = vtb + ((size_t)bh * 64 + row) * SS + s0 + c16;
  }
  *(bf16x8*)dst = o0;
  *(bf16x8*)(dst + 8) = o1;
}

// ---------------- 6. colsum (MFMA, split-s, LDS-free): cs[z][bh][t] ----------------
__global__ __launch_bounds__(256) void k_colsum_mfma(const ushort* __restrict__ qbf,
                                                     const ushort* __restrict__ kbf,
                                                     float* __restrict__ cs) {
  int bh = blockIdx.x, ttile = blockIdx.y, z = blockIdx.z;
  __shared__ float scs[4][4][16];
  int tid = threadIdx.x;
  int w = tid >> 6, l = tid & 63;
  int li = l & 15, g = l >> 4;
  const ushort* kb_base = kbf + ((size_t)bh * SS + ttile * 64) * 64;
  bf16x8 kb[4][2];
#pragma unroll
  for (int u = 0; u < 4; ++u)
#pragma unroll
    for (int kc = 0; kc < 2; ++kc)
      kb[u][kc] = *(const bf16x8*)(kb_base + (u * 16 + li) * 64 + kc * 32 + 8 * g);
  float cacc[4] = {0.f, 0.f, 0.f, 0.f};
  for (int it = 0; it < 16; ++it) {
    int s0 = ((z * 16 + it) * 4 + w) * 16;
    const ushort* qrow = qbf + ((size_t)bh * SS + s0 + li) * 64;
    bf16x8 qa0 = *(const bf16x8*)(qrow + 8 * g);
    bf16x8 qa1 = *(const bf16x8*)(qrow + 32 + 8 * g);
#pragma unroll
    for (int u = 0; u < 4; ++u) {
      __builtin_amdgcn_s_setprio(1);
      f32x4 cf = {0.f, 0.f, 0.f, 0.f};
      cf = __builtin_amdgcn_mfma_f32_16x16x32_bf16(qa0, kb[u][0], cf, 0, 0, 0);
      cf = __builtin_amdgcn_mfma_f32_16x16x32_bf16(qa1, kb[u][1], cf, 0, 0, 0);
      __builtin_amdgcn_s_setprio(0);
      float ww[4], pp[4];
#pragma unroll
      for (int r = 0; r < 4; ++r) score_wp(cf[r], ww[r], pp[r]);
      cacc[u] += __expf(ww[0] * pp[0]) + __expf(ww[1] * pp[1]) +
                 __expf(ww[2] * pp[2]) + __expf(ww[3] * pp[3]);
    }
  }
#pragma unroll
  for (int u = 0; u < 4; ++u) {
    cacc[u] += __shfl_xor(cacc[u], 16, 64);
    cacc[u] += __shfl_xor(cacc[u], 32, 64);
  }
  if (l < 16) {
#pragma unroll
    for (int u = 0; u < 4; ++u) scs[w][u][l] = cacc[u];
  }
  __syncthreads();
  if (tid < 64) {
    int t16 = tid & 15, u = tid >> 4;
    float s_ = scs[0][u][t16] + scs[1][u][t16] + scs[2][u][t16] + scs[3][u][t16];
    cs[(size_t)z * BHS + (size_t)bh * SS + ttile * 64 + u * 16 + t16] = s_;
  }
}

// ---------------- 7. lcw = -0.5*ln(colsum) ----------------
__global__ __launch_bounds__(256) void k_cwreduce(const float* __restrict__ cs,
                                                  float* __restrict__ lcw) {
  size_t g = (size_t)blockIdx.x * 256 + threadIdx.x;
  lcw[g] = -0.5f * __logf(cs[g] + cs[BHS + g]);
}

// ---------------- 8. attention (MFMA, split-t, T14 prefetch, T5 setprio) ----------------
__global__ __launch_bounds__(256) void k_attn_mfma(const ushort* __restrict__ qbf,
                                                   const ushort* __restrict__ kbf,
                                                   const ushort* __restrict__ vtb,
                                                   const float* __restrict__ lcw,
                                                   float* __restrict__ po0,
                                                   float* __restrict__ po1,
                                                   float* __restrict__ prp) {
  int bh = blockIdx.x, stile = blockIdx.y, z = blockIdx.z;
  __shared__ __align__(16) ushort Kt[64][72];            // stride 36 words = 4 mod 32 (optimal)
  __shared__ __align__(16) ushort Vt[64][72];
  __shared__ __align__(16) unsigned int W_lds[4][16][36];
  int tid = threadIdx.x;
  int w = tid >> 6, l = tid & 63;
  int li = l & 15, g = l >> 4;
  int s = stile * 64 + w * 16 + li;
  const ushort* qrow = qbf + ((size_t)bh * SS + s) * 64;
  bf16x8 qb0 = *(const bf16x8*)(qrow + 8 * g);
  bf16x8 qb1 = *(const bf16x8*)(qrow + 32 + 8 * g);
  const float* cwp = lcw + (size_t)bh * SS;
  const ushort* kb_h = kbf + (size_t)bh * SS * 64;
  const ushort* vt_h = vtb + (size_t)bh * 64 * SS;
  float* po = (z == 0) ? po0 : po1;
  int sr = tid >> 3, sc = (tid & 7) * 8;     // staging row/col
  f32x4 oacc[4];
#pragma unroll
  for (int dt = 0; dt < 4; ++dt) oacc[dt] = (f32x4){0.f, 0.f, 0.f, 0.f};
  float rp = 0.f;
  int tt0 = z * 16;
  // T14 prologue: loads for tile tt0
  bf16x8 rk0 = *(const bf16x8*)(kb_h + (size_t)(tt0 * 64 + sr) * 64 + sc);
  bf16x8 rk1 = *(const bf16x8*)(kb_h + (size_t)(tt0 * 64 + sr + 32) * 64 + sc);
  bf16x8 rv0 = *(const bf16x8*)(vt_h + (size_t)sr * SS + tt0 * 64 + sc);
  bf16x8 rv1 = *(const bf16x8*)(vt_h + (size_t)(sr + 32) * SS + tt0 * 64 + sc);
  for (int tt = tt0; tt < tt0 + 16; ++tt) {
    *(bf16x8*)&Kt[sr][sc] = rk0;
    *(bf16x8*)&Kt[sr + 32][sc] = rk1;
    *(bf16x8*)&Vt[sr][sc] = rv0;
    *(bf16x8*)&Vt[sr + 32][sc] = rv1;
    __syncthreads();
    if (tt + 1 < tt0 + 16) {   // issue next tile's loads; latency hides under compute
      rk0 = *(const bf16x8*)(kb_h + (size_t)((tt + 1) * 64 + sr) * 64 + sc);
      rk1 = *(const bf16x8*)(kb_h + (size_t)((tt + 1) * 64 + sr + 32) * 64 + sc);
      rv0 = *(const bf16x8*)(vt_h + (size_t)sr * SS + (tt + 1) * 64 + sc);
      rv1 = *(const bf16x8*)(vt_h + (size_t)(sr + 32) * SS + (tt + 1) * 64 + sc);
    }
#pragma unroll
    for (int u = 0; u < 4; ++u) {
      bf16x8 ka0 = *(const bf16x8*)&Kt[u * 16 + li][8 * g];
      bf16x8 ka1 = *(const bf16x8*)&Kt[u * 16 + li][32 + 8 * g];
      __builtin_amdgcn_s_setprio(1);
      f32x4 cf = {0.f, 0.f, 0.f, 0.f};
      cf = __builtin_amdgcn_mfma_f32_16x16x32_bf16(ka0, qb0, cf, 0, 0, 0);
      cf = __builtin_amdgcn_mfma_f32_16x16x32_bf16(ka1, qb1, cf, 0, 0, 0);
      __builtin_amdgcn_s_setprio(0);
      float4 lc4 = *(const float4*)(cwp + tt * 64 + u * 16 + 4 * g);
      float ww[4], pp[4];
#pragma unroll
      for (int r = 0; r < 4; ++r) score_wp(cf[r], ww[r], pp[r]);
      float s0_ = __expf(fmaf(ww[0], pp[0], lc4.x));
      float s1_ = __expf(fmaf(ww[1], pp[1], lc4.y));
      float s2_ = __expf(fmaf(ww[2], pp[2], lc4.z));
      float s3_ = __expf(fmaf(ww[3], pp[3], lc4.w));
      rp += s0_ + s1_ + s2_ + s3_;
      uint2 pw; pw.x = cvtpk_bf2(s0_, s1_); pw.y = cvtpk_bf2(s2_, s3_);
      *(uint2*)&W_lds[w][li][u * 8 + 2 * g] = pw;
    }
    __builtin_amdgcn_s_setprio(1);
#pragma unroll
    for (int tc = 0; tc < 2; ++tc) {
      bf16x8 bw = *(const bf16x8*)&W_lds[w][li][tc * 16 + 4 * g];
#pragma unroll
      for (int dt = 0; dt < 4; ++dt) {
        bf16x8 va = *(const bf16x8*)&Vt[dt * 16 + li][tc * 32 + 8 * g];
        oacc[dt] = __builtin_amdgcn_mfma_f32_16x16x32_bf16(va, bw, oacc[dt], 0, 0, 0);
      }
    }
    __builtin_amdgcn_s_setprio(0);
    __syncthreads();
  }
  // partial rowsum for col s: sum the 4 lane-groups
  rp += __shfl_xor(rp, 16, 64);
  rp += __shfl_xor(rp, 32, 64);
  if (l < 16)
    prp[(size_t)z * BHS + (size_t)bh * SS + stile * 64 + w * 16 + l] = rp;
  // partial O, [bh][d][s] layout
#pragma unroll
  for (int dt = 0; dt < 4; ++dt)
#pragma unroll
    for (int r = 0; r < 4; ++r)
      po[((size_t)bh * 64 + dt * 16 + 4 * g + r) * SS + s] = oacc[dt][r];
}

// ---------------- 9. combine halves -> bf16 attn-out (flat head-major) ----------------
__global__ __launch_bounds__(256) void k_combine(const float* __restrict__ po0,
                                                 const float* __restrict__ po1,
                                                 const float* __restrict__ prp,
                                                 ushort* __restrict__ aobf) {
  int s0 = blockIdx.x * 64, bh = blockIdx.y;
  __shared__ float rpl[64];
  __shared__ ushort t16[64][72];
  int tid = threadIdx.x;
  if (tid < 64) {
    float r = prp[(size_t)bh * SS + s0 + tid] + prp[BHS + (size_t)bh * SS + s0 + tid];
    rpl[tid] = 1.0f / fmaxf(r, 1e-12f);
  }
  __syncthreads();
#pragma unroll
  for (int i = 0; i < 16; ++i) {
    int flat = i * 256 + tid;
    int d = flat >> 4, sq = (flat & 15) * 4;
    size_t off = ((size_t)bh * 64 + d) * SS + s0 + sq;
    float4 p0 = *(const float4*)(po0 + off);
    float4 p1 = *(const float4*)(po1 + off);
    t16[sq + 0][d] = bf16_1((p0.x + p1.x) * rpl[sq + 0]);
    t16[sq + 1][d] = bf16_1((p0.y + p1.y) * rpl[sq + 1]);
    t16[sq + 2][d] = bf16_1((p0.z + p1.z) * rpl[sq + 2]);
    t16[sq + 3][d] = bf16_1((p0.w + p1.w) * rpl[sq + 3]);
  }
  __syncthreads();
  int s = tid >> 2, c = (tid & 3) * 16;
  bf16x8 o0 = *(const bf16x8*)&t16[s][c];
  bf16x8 o1 = *(const bf16x8*)&t16[s][c + 8];
  ushort* orow = aobf + ((size_t)bh * SS + s0 + s) * 64 + c;
  *(bf16x8*)orow = o0;
  *(bf16x8*)(orow + 8) = o1;
}

// ---------------- 10. output GEMM (bf16 MFMA, 2-phase LDS double-buffer) ----------------
__global__ __launch_bounds__(256) void k_gemm_out_mfma(
    const ushort* __restrict__ aob,
    const ushort* __restrict__ Wt,
    const float* __restrict__ bias,
    const float* __restrict__ hid,
    float* __restrict__ y) {
  int bid = blockIdx.x;
  int xcd = bid & 7; int rr = bid >> 3;
  int n_idx = rr % 12; int m_in = rr / 12;
  int n0 = n_idx * 64; int m0 = (xcd * 8 + m_in) * 64;
  __shared__ ushort As[2][64][72];
  __shared__ ushort Bs[2][64][72];
  int tid = threadIdx.x, w = tid >> 6, l = tid & 63, li = l & 15, g = l >> 4;
  int srow = tid >> 3, scol = (tid & 7) * 8;
  const ushort* Aba = aob + (size_t)(m0 + srow) * EE + scol;
  const ushort* Wba = Wt + (size_t)(n0 + srow) * EE + scol;
  f32x4 acc[4];
#pragma unroll
  for (int u = 0; u < 4; ++u) acc[u] = (f32x4){0.f, 0.f, 0.f, 0.f};
  bf16x8 pA0 = *(const bf16x8*)(Aba);
  bf16x8 pA1 = *(const bf16x8*)(Aba + 32 * EE);
  bf16x8 pW0 = *(const bf16x8*)(Wba);
  bf16x8 pW1 = *(const bf16x8*)(Wba + 32 * EE);
  *(bf16x8*)&As[0][srow][scol] = pA0;
  *(bf16x8*)&As[0][srow + 32][scol] = pA1;
  *(bf16x8*)&Bs[0][srow][scol] = pW0;
  *(bf16x8*)&Bs[0][srow + 32][scol] = pW1;
  __syncthreads();
#pragma unroll
  for (int kt = 0; kt < 12; ++kt) {
    int cur = kt & 1;
    if (kt < 11) {
      int k0 = (kt + 1) * 64;
      pA0 = *(const bf16x8*)(Aba + k0);
      pA1 = *(const bf16x8*)(Aba + 32 * EE + k0);
      pW0 = *(const bf16x8*)(Wba + k0);
      pW1 = *(const bf16x8*)(Wba + 32 * EE + k0);
    }
    bf16x8 a0 = *(const bf16x8*)&As[cur][w * 16 + li][8 * g];
    bf16x8 a1 = *(const bf16x8*)&As[cur][w * 16 + li][32 + 8 * g];
#pragma unroll
    for (int u = 0; u < 4; ++u) {
      bf16x8 bb0 = *(const bf16x8*)&Bs[cur][u * 16 + li][8 * g];
      bf16x8 bb1 = *(const bf16x8*)&Bs[cur][u * 16 + li][32 + 8 * g];
      acc[u] = __builtin_amdgcn_mfma_f32_16x16x32_bf16(a0, bb0, acc[u], 0, 0, 0);
      acc[u] = __builtin_amdgcn_mfma_f32_16x16x32_bf16(a1, bb1, acc[u], 0, 0, 0);
    }
    __syncthreads();
    if (kt < 11) {
      int nxt = cur ^ 1;
      *(bf16x8*)&As[nxt][srow][scol] = pA0;
      *(bf16x8*)&As[nxt][srow + 32][scol] = pA1;
      *(bf16x8*)&Bs[nxt][srow][scol] = pW0;
      *(bf16x8*)&Bs[nxt][srow + 32][scol] = pW1;
      __syncthreads();
    }
  }
  int m_base = m0 + w * 16 + 4 * g;
#pragma unroll
  for (int u = 0; u < 4; ++u) {
    int n = n0 + u * 16 + li;
    float bia = bias[n];
#pragma unroll
    for (int r = 0; r < 4; ++r) {
      int m = m_base + r;
      y[(size_t)m * EE + n] = acc[u][r] + bia + hid[(size_t)m * EE + n];
    }
  }
}

// ---------------- 11. LayerNorm -> float32 out ----------------
__global__ __launch_bounds__(256) void k_ln(const float* __restrict__ y,
                                            const float* __restrict__ g,
                                            const float* __restrict__ b,
                                            float* __restrict__ out) {
  int row = blockIdx.x;
  int tid = threadIdx.x;
  const float* yr = y + (size_t)row * EE;
  float v0 = yr[tid], v1 = yr[tid + 256], v2 = yr[tid + 512];
  float s1 = v0 + v1 + v2;
  float s2 = v0 * v0 + v1 * v1 + v2 * v2;
#pragma unroll
  for (int off = 32; off > 0; off >>= 1) {
    s1 += __shfl_down(s1, off, 64);
    s2 += __shfl_down(s2, off, 64);
  }
  __shared__ float r1[4], r2[4];
  if ((tid & 63) == 0) { r1[tid >> 6] = s1; r2[tid >> 6] = s2; }
  __syncthreads();
  float S1 = r1[0] + r1[1] + r1[2] + r1[3];
  float S2 = r2[0] + r2[1] + r2[2] + r2[3];
  float mu = S1 * (1.0f / 768.0f);
  float var = fmaxf(S2 * (1.0f / 768.0f) - mu * mu, 0.0f);
  float rstd = 1.0f / sqrtf(var + 1e-12f);
  float* orow = out + (size_t)row * EE;
  orow[tid]       = (v0 - mu) * rstd * g[tid]       + b[tid];
  orow[tid + 256] = (v1 - mu) * rstd * g[tid + 256] + b[tid + 256];
  orow[tid + 512] = (v2 - mu) * rstd * g[tid + 512] + b[tid + 512];
}

extern "C" void kernel_launch(void* const* d_in, const int* in_sizes, int n_in,
                              void* d_out, int out_size, void* d_ws, size_t ws_size,
                              hipStream_t stream) {
  const float* hidden = (const float*)d_in[0];
  const float* Wq = (const float*)d_in[1];
  const float* bq = (const float*)d_in[2];
  const float* Wk = (const float*)d_in[3];
  const float* bk = (const float*)d_in[4];
  const float* Wv = (const float*)d_in[5];
  const float* bv = (const float*)d_in[6];
  const float* Wo = (const float*)d_in[7];
  const float* bo = (const float*)d_in[8];
  const float* lng = (const float*)d_in[9];
  const float* lnb = (const float*)d_in[10];
  float* out = (float*)d_out;

  float* ws = (float*)d_ws;
  size_t need = (5 * NM + BHS) * sizeof(float);
  if (ws_size < need) return;

  ushort* hsb = (ushort*)ws;
  ushort* wt  = (ushort*)(ws + NM / 2);
  float* ws1 = ws + 1 * NM;   // cs -> po0 -> y
  float* ws2 = ws + 2 * NM;   // po1
  float* ws3 = ws + 3 * NM;   // qbf | vtb
  float* ws4 = ws + 4 * NM;   // kbf->aobf | prp
  float* lcw = ws + 5 * NM;   // [BH*SS]

  ushort* qbf = (ushort*)ws3;
  ushort* vtb = (ushort*)(ws3 + NM / 2);
  ushort* kbf = (ushort*)ws4;
  float* cs = ws1;
  float* po0 = ws1;
  float* po1 = ws2;
  float* prp = ws4 + NM / 2;
  ushort* aobf = (ushort*)ws4;
  float* y = ws1;

  hipLaunchKernelGGL(k_rownorm, dim3(MM), dim3(256), 0, stream, hidden, hsb);
  hipLaunchKernelGGL(k_transp, dim3(EE / 64, EE / 64, 4), dim3(256), 0, stream,
                     Wq, Wk, Wv, Wo, wt);
  hipLaunchKernelGGL(k_gemm_qkv_mfma, dim3(2304), dim3(256), 0, stream,
                     hsb, wt, bq, bk, bv, qbf, kbf, vtb);
  hipLaunchKernelGGL(k_colsum_mfma, dim3(BH, 32, 2), dim3(256), 0, stream,
                     qbf, kbf, cs);
  hipLaunchKernelGGL(k_cwreduce, dim3(BHS / 256), dim3(256), 0, stream, cs, lcw);
  hipLaunchKernelGGL(k_attn_mfma, dim3(BH, 32, 2), dim3(256), 0, stream,
                     qbf, kbf, vtb, lcw, po0, po1, prp);
  hipLaunchKernelGGL(k_combine, dim3(SS / 64, BH), dim3(256), 0, stream,
                     po0, po1, prp, aobf);
  hipLaunchKernelGGL(k_gemm_out_mfma, dim3(768), dim3(256), 0, stream,
                     aobf, wt + 3 * WSZ, bo, hidden, y);
  hipLaunchKernelGGL(k_ln, dim3(MM), dim3(256), 0, stream, y, lng, lnb, out);
}

// Round 18
// 171.016 us; speedup vs baseline: 1.0313x; 1.0313x over previous
//
#include <hip/hip_runtime.h>
#include <hip/hip_bf16.h>
#include <math.h>

#define BB 2
#define SS 2048
#define EE 768
#define HH 12
#define DD 64
#define MM (BB*SS)          // 4096 rows
#define BH (BB*HH)          // 24 heads total
#define NM ((size_t)MM*EE)  // 3145728 elements per [B,S,E] buffer
#define WSZ ((size_t)EE*EE) // 589824 weight elements
#define BHS ((size_t)BH*SS) // 49152

typedef __attribute__((ext_vector_type(8))) short bf16x8;   // 8 bf16 in 4 VGPR
typedef __attribute__((ext_vector_type(4))) float f32x4;    // MFMA C/D frag

// ---------------- helpers ----------------
__device__ __forceinline__ float wave_sum64(float v) {
#pragma unroll
  for (int off = 32; off > 0; off >>= 1) v += __shfl_down(v, off, 64);
  return v;
}

__device__ __forceinline__ unsigned int pack_bf2(float x, float y) {
  unsigned int a = __float_as_uint(x), b = __float_as_uint(y);
  a += 0x7fffu + ((a >> 16) & 1u);
  b += 0x7fffu + ((b >> 16) & 1u);
  return (a >> 16) | (b & 0xffff0000u);
}
__device__ __forceinline__ unsigned int cvtpk_bf2(float x, float y) {
  __hip_bfloat162 h = __float22bfloat162_rn(make_float2(x, y));
  union { __hip_bfloat162 h2; unsigned int u; } c; c.h2 = h;
  return c.u;
}
__device__ __forceinline__ ushort bf16_1(float x) {
  unsigned int u = __float_as_uint(x);
  u += 0x7fffu + ((u >> 16) & 1u);
  return (ushort)(u >> 16);
}

// -acos(x)^2 = w * p(w), w = (1-x)/2.  5-op natural-domain poly (asin^2 series,
// tail minimax-bumped: -4(1 + w/3 + 8w^2/45 + 4w^3/35 + 0.154w^4)).
// score = __expf(w*p + lcw), lcw = -0.5*ln(colsum).
__device__ __forceinline__ void score_wp(float cosv, float& w, float& p) {
  w = fmaxf(fmaf(cosv, -0.5f, 0.5f), 0.0f);
  p = fmaf(w, -0.616000f, -0.4571429f);
  p = fmaf(w, p, -0.7111111f);
  p = fmaf(w, p, -1.3333333f);
  p = fmaf(w, p, -4.0f);
}

// ---------------- 1. row l2-norm over E -> bf16 ----------------
__global__ __launch_bounds__(256) void k_rownorm(const float* __restrict__ x,
                                                 ushort* __restrict__ o) {
  int row = blockIdx.x;
  int tid = threadIdx.x;
  const float* xr = x + (size_t)row * EE;
  ushort* orow = o + (size_t)row * EE;
  float v0 = xr[tid], v1 = xr[tid + 256], v2 = xr[tid + 512];
  float ss = v0 * v0 + v1 * v1 + v2 * v2;
  ss = wave_sum64(ss);
  __shared__ float red[4];
  if ((tid & 63) == 0) red[tid >> 6] = ss;
  __syncthreads();
  float tot = red[0] + red[1] + red[2] + red[3];
  float sc = 1.0f / fmaxf(sqrtf(tot), 1e-12f);
  orow[tid]       = bf16_1(v0 * sc);
  orow[tid + 256] = bf16_1(v1 * sc);
  orow[tid + 512] = bf16_1(v2 * sc);
}

// ---------------- 2. weight transpose -> bf16 Wt[n][k] ----------------
__global__ __launch_bounds__(256) void k_transp(const float* __restrict__ Wq,
                                                const float* __restrict__ Wk,
                                                const float* __restrict__ Wv,
                                                const float* __restrict__ Wo,
                                                ushort* __restrict__ wt) {
  int z = blockIdx.z;
  const float* W = (z == 0) ? Wq : (z == 1) ? Wk : (z == 2) ? Wv : Wo;
  ushort* dst = wt + (size_t)z * WSZ;
  int n0 = blockIdx.x * 64, k0 = blockIdx.y * 64;
  __shared__ float t[64][65];
  int tid = threadIdx.x;
  int r4 = tid >> 4, c4 = (tid & 15) * 4;
#pragma unroll
  for (int i = 0; i < 4; ++i) {
    float4 v = *(const float4*)(W + (size_t)(k0 + i * 16 + r4) * EE + n0 + c4);
    t[i * 16 + r4][c4 + 0] = v.x; t[i * 16 + r4][c4 + 1] = v.y;
    t[i * 16 + r4][c4 + 2] = v.z; t[i * 16 + r4][c4 + 3] = v.w;
  }
  __syncthreads();
  int nr = tid >> 3, c8 = (tid & 7) * 8;
#pragma unroll
  for (int j = 0; j < 2; ++j) {
    int n = nr + j * 32;
    unsigned int p[4];
#pragma unroll
    for (int e = 0; e < 4; ++e)
      p[e] = pack_bf2(t[c8 + 2 * e][n], t[c8 + 2 * e + 1][n]);
    uint4 pv; pv.x = p[0]; pv.y = p[1]; pv.z = p[2]; pv.w = p[3];
    *(uint4*)(dst + (size_t)(n0 + n) * EE + k0 + c8) = pv;
  }
}

// ---------------- 3. QKV GEMM (bf16 MFMA, 2-phase LDS double-buffer) ----
__global__ __launch_bounds__(256) void k_gemm_qkv_mfma(
    const ushort* __restrict__ hsb,
    const ushort* __restrict__ wt,
    const float* __restrict__ b0, const float* __restrict__ b1, const float* __restrict__ b2,
    ushort* __restrict__ qb, ushort* __restrict__ kb, ushort* __restrict__ vtb) {
  int bid = blockIdx.x;
  int xcd = bid & 7; int rr = bid >> 3;
  int n_idx = rr % 12; int m_in = (rr / 12) & 7; int z = rr / 96;
  int n0 = n_idx * 64; int m0 = (xcd * 8 + m_in) * 64;
  const ushort* W = wt + (size_t)z * WSZ;
  const float* bias = (z == 0) ? b0 : (z == 1) ? b1 : b2;
  __shared__ ushort As[2][64][72];
  __shared__ ushort Bs[2][64][72];
  int tid = threadIdx.x, w = tid >> 6, l = tid & 63, li = l & 15, g = l >> 4;
  int srow = tid >> 3, scol = (tid & 7) * 8;
  const ushort* Aba = hsb + (size_t)(m0 + srow) * EE + scol;
  const ushort* Wba = W + (size_t)(n0 + srow) * EE + scol;
  f32x4 acc[4];
#pragma unroll
  for (int u = 0; u < 4; ++u) acc[u] = (f32x4){0.f, 0.f, 0.f, 0.f};
  bf16x8 pA0 = *(const bf16x8*)(Aba);
  bf16x8 pA1 = *(const bf16x8*)(Aba + 32 * EE);
  bf16x8 pW0 = *(const bf16x8*)(Wba);
  bf16x8 pW1 = *(const bf16x8*)(Wba + 32 * EE);
  *(bf16x8*)&As[0][srow][scol] = pA0;
  *(bf16x8*)&As[0][srow + 32][scol] = pA1;
  *(bf16x8*)&Bs[0][srow][scol] = pW0;
  *(bf16x8*)&Bs[0][srow + 32][scol] = pW1;
  __syncthreads();
#pragma unroll
  for (int kt = 0; kt < 12; ++kt) {
    int cur = kt & 1;
    if (kt < 11) {
      int k0 = (kt + 1) * 64;
      pA0 = *(const bf16x8*)(Aba + k0);
      pA1 = *(const bf16x8*)(Aba + 32 * EE + k0);
      pW0 = *(const bf16x8*)(Wba + k0);
      pW1 = *(const bf16x8*)(Wba + 32 * EE + k0);
    }
    bf16x8 a0 = *(const bf16x8*)&As[cur][w * 16 + li][8 * g];
    bf16x8 a1 = *(const bf16x8*)&As[cur][w * 16 + li][32 + 8 * g];
#pragma unroll
    for (int u = 0; u < 4; ++u) {
      bf16x8 bb0 = *(const bf16x8*)&Bs[cur][u * 16 + li][8 * g];
      bf16x8 bb1 = *(const bf16x8*)&Bs[cur][u * 16 + li][32 + 8 * g];
      acc[u] = __builtin_amdgcn_mfma_f32_16x16x32_bf16(a0, bb0, acc[u], 0, 0, 0);
      acc[u] = __builtin_amdgcn_mfma_f32_16x16x32_bf16(a1, bb1, acc[u], 0, 0, 0);
    }
    __syncthreads();
    if (kt < 11) {
      int nxt = cur ^ 1;
      *(bf16x8*)&As[nxt][srow][scol] = pA0;
      *(bf16x8*)&As[nxt][srow + 32][scol] = pA1;
      *(bf16x8*)&Bs[nxt][srow][scol] = pW0;
      *(bf16x8*)&Bs[nxt][srow + 32][scol] = pW1;
      __syncthreads();
    }
  }
  float val[4][4];
#pragma unroll
  for (int u = 0; u < 4; ++u) {
    float bia = bias[n0 + u * 16 + li];
#pragma unroll
    for (int r = 0; r < 4; ++r) val[u][r] = acc[u][r] + bia;
  }
  if (z < 2) {
#pragma unroll
    for (int r = 0; r < 4; ++r) {
      float ss = val[0][r] * val[0][r] + val[1][r] * val[1][r] +
                 val[2][r] * val[2][r] + val[3][r] * val[3][r];
      ss += __shfl_xor(ss, 1, 64);
      ss += __shfl_xor(ss, 2, 64);
      ss += __shfl_xor(ss, 4, 64);
      ss += __shfl_xor(ss, 8, 64);
      float sc = rsqrtf(fmaxf(ss, 1e-24f));
#pragma unroll
      for (int u = 0; u < 4; ++u) val[u][r] *= sc;
    }
  }
  ushort (*tile)[72] = As[0];
#pragma unroll
  for (int u = 0; u < 4; ++u)
#pragma unroll
    for (int r = 0; r < 4; ++r) {
      int ml = w * 16 + 4 * g + r, d = u * 16 + li;
      if (z < 2) tile[ml][d] = bf16_1(val[u][r]);
      else       tile[d][ml] = bf16_1(val[u][r]);
    }
  __syncthreads();
  int h = n_idx, b_ = m0 >> 11, s0 = m0 & 2047;
  int bh = b_ * HH + h;
  int row = tid >> 2, c16 = (tid & 3) * 16;
  bf16x8 o0 = *(const bf16x8*)&tile[row][c16];
  bf16x8 o1 = *(const bf16x8*)&tile[row][c16 + 8];
  ushort* dst;
  if (z < 2) {
    dst = (z ? kb : qb) + ((size_t)bh * SS + s0 + row) * 64 + c16;
  } else {
    dst = vtb + ((size_t)bh * 64 + row) * SS + s0 + c16;
  }
  *(bf16x8*)dst = o0;
  *(bf16x8*)(dst + 8) = o1;
}

// ---------------- 6. colsum (MFMA, split-s, LDS-free): cs[z][bh][t] ----------------
__global__ __launch_bounds__(256) void k_colsum_mfma(const ushort* __restrict__ qbf,
                                                     const ushort* __restrict__ kbf,
                                                     float* __restrict__ cs) {
  int bh = blockIdx.x, ttile = blockIdx.y, z = blockIdx.z;
  __shared__ float scs[4][4][16];
  int tid = threadIdx.x;
  int w = tid >> 6, l = tid & 63;
  int li = l & 15, g = l >> 4;
  const ushort* kb_base = kbf + ((size_t)bh * SS + ttile * 64) * 64;
  bf16x8 kb[4][2];
#pragma unroll
  for (int u = 0; u < 4; ++u)
#pragma unroll
    for (int kc = 0; kc < 2; ++kc)
      kb[u][kc] = *(const bf16x8*)(kb_base + (u * 16 + li) * 64 + kc * 32 + 8 * g);
  float cacc[4] = {0.f, 0.f, 0.f, 0.f};
  for (int it = 0; it < 16; ++it) {
    int s0 = ((z * 16 + it) * 4 + w) * 16;
    const ushort* qrow = qbf + ((size_t)bh * SS + s0 + li) * 64;
    bf16x8 qa0 = *(const bf16x8*)(qrow + 8 * g);
    bf16x8 qa1 = *(const bf16x8*)(qrow + 32 + 8 * g);
#pragma unroll
    for (int u = 0; u < 4; ++u) {
      f32x4 cf = {0.f, 0.f, 0.f, 0.f};
      cf = __builtin_amdgcn_mfma_f32_16x16x32_bf16(qa0, kb[u][0], cf, 0, 0, 0);
      cf = __builtin_amdgcn_mfma_f32_16x16x32_bf16(qa1, kb[u][1], cf, 0, 0, 0);
      float ww[4], pp[4];
#pragma unroll
      for (int r = 0; r < 4; ++r) score_wp(cf[r], ww[r], pp[r]);
      cacc[u] += __expf(ww[0] * pp[0]) + __expf(ww[1] * pp[1]) +
                 __expf(ww[2] * pp[2]) + __expf(ww[3] * pp[3]);
    }
  }
#pragma unroll
  for (int u = 0; u < 4; ++u) {
    cacc[u] += __shfl_xor(cacc[u], 16, 64);
    cacc[u] += __shfl_xor(cacc[u], 32, 64);
  }
  if (l < 16) {
#pragma unroll
    for (int u = 0; u < 4; ++u) scs[w][u][l] = cacc[u];
  }
  __syncthreads();
  if (tid < 64) {
    int t16 = tid & 15, u = tid >> 4;
    float s_ = scs[0][u][t16] + scs[1][u][t16] + scs[2][u][t16] + scs[3][u][t16];
    cs[(size_t)z * BHS + (size_t)bh * SS + ttile * 64 + u * 16 + t16] = s_;
  }
}

// ---------------- 7. lcw = -0.5*ln(colsum) ----------------
__global__ __launch_bounds__(256) void k_cwreduce(const float* __restrict__ cs,
                                                  float* __restrict__ lcw) {
  size_t g = (size_t)blockIdx.x * 256 + threadIdx.x;
  lcw[g] = -0.5f * __logf(cs[g] + cs[BHS + g]);
}

// ---------------- 8. attention (MFMA, split-t, T14 prefetch, 72-pad LDS) ----------------
__global__ __launch_bounds__(256) void k_attn_mfma(const ushort* __restrict__ qbf,
                                                   const ushort* __restrict__ kbf,
                                                   const ushort* __restrict__ vtb,
                                                   const float* __restrict__ lcw,
                                                   float* __restrict__ po0,
                                                   float* __restrict__ po1,
                                                   float* __restrict__ prp) {
  int bh = blockIdx.x, stile = blockIdx.y, z = blockIdx.z;
  __shared__ __align__(16) ushort Kt[64][72];            // stride 36 words = 4 mod 32 (optimal)
  __shared__ __align__(16) ushort Vt[64][72];
  __shared__ __align__(16) unsigned int W_lds[4][16][36];
  int tid = threadIdx.x;
  int w = tid >> 6, l = tid & 63;
  int li = l & 15, g = l >> 4;
  int s = stile * 64 + w * 16 + li;
  const ushort* qrow = qbf + ((size_t)bh * SS + s) * 64;
  bf16x8 qb0 = *(const bf16x8*)(qrow + 8 * g);
  bf16x8 qb1 = *(const bf16x8*)(qrow + 32 + 8 * g);
  const float* cwp = lcw + (size_t)bh * SS;
  const ushort* kb_h = kbf + (size_t)bh * SS * 64;
  const ushort* vt_h = vtb + (size_t)bh * 64 * SS;
  float* po = (z == 0) ? po0 : po1;
  int sr = tid >> 3, sc = (tid & 7) * 8;     // staging row/col
  f32x4 oacc[4];
#pragma unroll
  for (int dt = 0; dt < 4; ++dt) oacc[dt] = (f32x4){0.f, 0.f, 0.f, 0.f};
  float rp = 0.f;
  int tt0 = z * 16;
  // T14 prologue: loads for tile tt0
  bf16x8 rk0 = *(const bf16x8*)(kb_h + (size_t)(tt0 * 64 + sr) * 64 + sc);
  bf16x8 rk1 = *(const bf16x8*)(kb_h + (size_t)(tt0 * 64 + sr + 32) * 64 + sc);
  bf16x8 rv0 = *(const bf16x8*)(vt_h + (size_t)sr * SS + tt0 * 64 + sc);
  bf16x8 rv1 = *(const bf16x8*)(vt_h + (size_t)(sr + 32) * SS + tt0 * 64 + sc);
  for (int tt = tt0; tt < tt0 + 16; ++tt) {
    *(bf16x8*)&Kt[sr][sc] = rk0;
    *(bf16x8*)&Kt[sr + 32][sc] = rk1;
    *(bf16x8*)&Vt[sr][sc] = rv0;
    *(bf16x8*)&Vt[sr + 32][sc] = rv1;
    __syncthreads();
    if (tt + 1 < tt0 + 16) {   // issue next tile's loads; latency hides under compute
      rk0 = *(const bf16x8*)(kb_h + (size_t)((tt + 1) * 64 + sr) * 64 + sc);
      rk1 = *(const bf16x8*)(kb_h + (size_t)((tt + 1) * 64 + sr + 32) * 64 + sc);
      rv0 = *(const bf16x8*)(vt_h + (size_t)sr * SS + (tt + 1) * 64 + sc);
      rv1 = *(const bf16x8*)(vt_h + (size_t)(sr + 32) * SS + (tt + 1) * 64 + sc);
    }
#pragma unroll
    for (int u = 0; u < 4; ++u) {
      bf16x8 ka0 = *(const bf16x8*)&Kt[u * 16 + li][8 * g];
      bf16x8 ka1 = *(const bf16x8*)&Kt[u * 16 + li][32 + 8 * g];
      f32x4 cf = {0.f, 0.f, 0.f, 0.f};
      cf = __builtin_amdgcn_mfma_f32_16x16x32_bf16(ka0, qb0, cf, 0, 0, 0);
      cf = __builtin_amdgcn_mfma_f32_16x16x32_bf16(ka1, qb1, cf, 0, 0, 0);
      float4 lc4 = *(const float4*)(cwp + tt * 64 + u * 16 + 4 * g);
      float ww[4], pp[4];
#pragma unroll
      for (int r = 0; r < 4; ++r) score_wp(cf[r], ww[r], pp[r]);
      float s0_ = __expf(fmaf(ww[0], pp[0], lc4.x));
      float s1_ = __expf(fmaf(ww[1], pp[1], lc4.y));
      float s2_ = __expf(fmaf(ww[2], pp[2], lc4.z));
      float s3_ = __expf(fmaf(ww[3], pp[3], lc4.w));
      rp += s0_ + s1_ + s2_ + s3_;
      uint2 pw; pw.x = cvtpk_bf2(s0_, s1_); pw.y = cvtpk_bf2(s2_, s3_);
      *(uint2*)&W_lds[w][li][u * 8 + 2 * g] = pw;
    }
#pragma unroll
    for (int tc = 0; tc < 2; ++tc) {
      bf16x8 bw = *(const bf16x8*)&W_lds[w][li][tc * 16 + 4 * g];
#pragma unroll
      for (int dt = 0; dt < 4; ++dt) {
        bf16x8 va = *(const bf16x8*)&Vt[dt * 16 + li][tc * 32 + 8 * g];
        oacc[dt] = __builtin_amdgcn_mfma_f32_16x16x32_bf16(va, bw, oacc[dt], 0, 0, 0);
      }
    }
    __syncthreads();
  }
  // partial rowsum for col s: sum the 4 lane-groups
  rp += __shfl_xor(rp, 16, 64);
  rp += __shfl_xor(rp, 32, 64);
  if (l < 16)
    prp[(size_t)z * BHS + (size_t)bh * SS + stile * 64 + w * 16 + l] = rp;
  // partial O, [bh][d][s] layout
#pragma unroll
  for (int dt = 0; dt < 4; ++dt)
#pragma unroll
    for (int r = 0; r < 4; ++r)
      po[((size_t)bh * 64 + dt * 16 + 4 * g + r) * SS + s] = oacc[dt][r];
}

// ---------------- 9. combine halves -> bf16 attn-out (flat head-major) ----------------
__global__ __launch_bounds__(256) void k_combine(const float* __restrict__ po0,
                                                 const float* __restrict__ po1,
                                                 const float* __restrict__ prp,
                                                 ushort* __restrict__ aobf) {
  int s0 = blockIdx.x * 64, bh = blockIdx.y;
  __shared__ float rpl[64];
  __shared__ ushort t16[64][72];
  int tid = threadIdx.x;
  if (tid < 64) {
    float r = prp[(size_t)bh * SS + s0 + tid] + prp[BHS + (size_t)bh * SS + s0 + tid];
    rpl[tid] = 1.0f / fmaxf(r, 1e-12f);
  }
  __syncthreads();
#pragma unroll
  for (int i = 0; i < 16; ++i) {
    int flat = i * 256 + tid;
    int d = flat >> 4, sq = (flat & 15) * 4;
    size_t off = ((size_t)bh * 64 + d) * SS + s0 + sq;
    float4 p0 = *(const float4*)(po0 + off);
    float4 p1 = *(const float4*)(po1 + off);
    t16[sq + 0][d] = bf16_1((p0.x + p1.x) * rpl[sq + 0]);
    t16[sq + 1][d] = bf16_1((p0.y + p1.y) * rpl[sq + 1]);
    t16[sq + 2][d] = bf16_1((p0.z + p1.z) * rpl[sq + 2]);
    t16[sq + 3][d] = bf16_1((p0.w + p1.w) * rpl[sq + 3]);
  }
  __syncthreads();
  int s = tid >> 2, c = (tid & 3) * 16;
  bf16x8 o0 = *(const bf16x8*)&t16[s][c];
  bf16x8 o1 = *(const bf16x8*)&t16[s][c + 8];
  ushort* orow = aobf + ((size_t)bh * SS + s0 + s) * 64 + c;
  *(bf16x8*)orow = o0;
  *(bf16x8*)(orow + 8) = o1;
}

// ---------------- 10. output GEMM (bf16 MFMA, 2-phase LDS double-buffer) ----------------
__global__ __launch_bounds__(256) void k_gemm_out_mfma(
    const ushort* __restrict__ aob,
    const ushort* __restrict__ Wt,
    const float* __restrict__ bias,
    const float* __restrict__ hid,
    float* __restrict__ y) {
  int bid = blockIdx.x;
  int xcd = bid & 7; int rr = bid >> 3;
  int n_idx = rr % 12; int m_in = rr / 12;
  int n0 = n_idx * 64; int m0 = (xcd * 8 + m_in) * 64;
  __shared__ ushort As[2][64][72];
  __shared__ ushort Bs[2][64][72];
  int tid = threadIdx.x, w = tid >> 6, l = tid & 63, li = l & 15, g = l >> 4;
  int srow = tid >> 3, scol = (tid & 7) * 8;
  const ushort* Aba = aob + (size_t)(m0 + srow) * EE + scol;
  const ushort* Wba = Wt + (size_t)(n0 + srow) * EE + scol;
  f32x4 acc[4];
#pragma unroll
  for (int u = 0; u < 4; ++u) acc[u] = (f32x4){0.f, 0.f, 0.f, 0.f};
  bf16x8 pA0 = *(const bf16x8*)(Aba);
  bf16x8 pA1 = *(const bf16x8*)(Aba + 32 * EE);
  bf16x8 pW0 = *(const bf16x8*)(Wba);
  bf16x8 pW1 = *(const bf16x8*)(Wba + 32 * EE);
  *(bf16x8*)&As[0][srow][scol] = pA0;
  *(bf16x8*)&As[0][srow + 32][scol] = pA1;
  *(bf16x8*)&Bs[0][srow][scol] = pW0;
  *(bf16x8*)&Bs[0][srow + 32][scol] = pW1;
  __syncthreads();
#pragma unroll
  for (int kt = 0; kt < 12; ++kt) {
    int cur = kt & 1;
    if (kt < 11) {
      int k0 = (kt + 1) * 64;
      pA0 = *(const bf16x8*)(Aba + k0);
      pA1 = *(const bf16x8*)(Aba + 32 * EE + k0);
      pW0 = *(const bf16x8*)(Wba + k0);
      pW1 = *(const bf16x8*)(Wba + 32 * EE + k0);
    }
    bf16x8 a0 = *(const bf16x8*)&As[cur][w * 16 + li][8 * g];
    bf16x8 a1 = *(const bf16x8*)&As[cur][w * 16 + li][32 + 8 * g];
#pragma unroll
    for (int u = 0; u < 4; ++u) {
      bf16x8 bb0 = *(const bf16x8*)&Bs[cur][u * 16 + li][8 * g];
      bf16x8 bb1 = *(const bf16x8*)&Bs[cur][u * 16 + li][32 + 8 * g];
      acc[u] = __builtin_amdgcn_mfma_f32_16x16x32_bf16(a0, bb0, acc[u], 0, 0, 0);
      acc[u] = __builtin_amdgcn_mfma_f32_16x16x32_bf16(a1, bb1, acc[u], 0, 0, 0);
    }
    __syncthreads();
    if (kt < 11) {
      int nxt = cur ^ 1;
      *(bf16x8*)&As[nxt][srow][scol] = pA0;
      *(bf16x8*)&As[nxt][srow + 32][scol] = pA1;
      *(bf16x8*)&Bs[nxt][srow][scol] = pW0;
      *(bf16x8*)&Bs[nxt][srow + 32][scol] = pW1;
      __syncthreads();
    }
  }
  int m_base = m0 + w * 16 + 4 * g;
#pragma unroll
  for (int u = 0; u < 4; ++u) {
    int n = n0 + u * 16 + li;
    float bia = bias[n];
#pragma unroll
    for (int r = 0; r < 4; ++r) {
      int m = m_base + r;
      y[(size_t)m * EE + n] = acc[u][r] + bia + hid[(size_t)m * EE + n];
    }
  }
}

// ---------------- 11. LayerNorm -> float32 out ----------------
__global__ __launch_bounds__(256) void k_ln(const float* __restrict__ y,
                                            const float* __restrict__ g,
                                            const float* __restrict__ b,
                                            float* __restrict__ out) {
  int row = blockIdx.x;
  int tid = threadIdx.x;
  const float* yr = y + (size_t)row * EE;
  float v0 = yr[tid], v1 = yr[tid + 256], v2 = yr[tid + 512];
  float s1 = v0 + v1 + v2;
  float s2 = v0 * v0 + v1 * v1 + v2 * v2;
#pragma unroll
  for (int off = 32; off > 0; off >>= 1) {
    s1 += __shfl_down(s1, off, 64);
    s2 += __shfl_down(s2, off, 64);
  }
  __shared__ float r1[4], r2[4];
  if ((tid & 63) == 0) { r1[tid >> 6] = s1; r2[tid >> 6] = s2; }
  __syncthreads();
  float S1 = r1[0] + r1[1] + r1[2] + r1[3];
  float S2 = r2[0] + r2[1] + r2[2] + r2[3];
  float mu = S1 * (1.0f / 768.0f);
  float var = fmaxf(S2 * (1.0f / 768.0f) - mu * mu, 0.0f);
  float rstd = 1.0f / sqrtf(var + 1e-12f);
  float* orow = out + (size_t)row * EE;
  orow[tid]       = (v0 - mu) * rstd * g[tid]       + b[tid];
  orow[tid + 256] = (v1 - mu) * rstd * g[tid + 256] + b[tid + 256];
  orow[tid + 512] = (v2 - mu) * rstd * g[tid + 512] + b[tid + 512];
}

extern "C" void kernel_launch(void* const* d_in, const int* in_sizes, int n_in,
                              void* d_out, int out_size, void* d_ws, size_t ws_size,
                              hipStream_t stream) {
  const float* hidden = (const float*)d_in[0];
  const float* Wq = (const float*)d_in[1];
  const float* bq = (const float*)d_in[2];
  const float* Wk = (const float*)d_in[3];
  const float* bk = (const float*)d_in[4];
  const float* Wv = (const float*)d_in[5];
  const float* bv = (const float*)d_in[6];
  const float* Wo = (const float*)d_in[7];
  const float* bo = (const float*)d_in[8];
  const float* lng = (const float*)d_in[9];
  const float* lnb = (const float*)d_in[10];
  float* out = (float*)d_out;

  float* ws = (float*)d_ws;
  size_t need = (5 * NM + BHS) * sizeof(float);
  if (ws_size < need) return;

  ushort* hsb = (ushort*)ws;
  ushort* wt  = (ushort*)(ws + NM / 2);
  float* ws1 = ws + 1 * NM;   // cs -> po0 -> y
  float* ws2 = ws + 2 * NM;   // po1
  float* ws3 = ws + 3 * NM;   // qbf | vtb
  float* ws4 = ws + 4 * NM;   // kbf->aobf | prp
  float* lcw = ws + 5 * NM;   // [BH*SS]

  ushort* qbf = (ushort*)ws3;
  ushort* vtb = (ushort*)(ws3 + NM / 2);
  ushort* kbf = (ushort*)ws4;
  float* cs = ws1;
  float* po0 = ws1;
  float* po1 = ws2;
  float* prp = ws4 + NM / 2;
  ushort* aobf = (ushort*)ws4;
  float* y = ws1;

  hipLaunchKernelGGL(k_rownorm, dim3(MM), dim3(256), 0, stream, hidden, hsb);
  hipLaunchKernelGGL(k_transp, dim3(EE / 64, EE / 64, 4), dim3(256), 0, stream,
                     Wq, Wk, Wv, Wo, wt);
  hipLaunchKernelGGL(k_gemm_qkv_mfma, dim3(2304), dim3(256), 0, stream,
                     hsb, wt, bq, bk, bv, qbf, kbf, vtb);
  hipLaunchKernelGGL(k_colsum_mfma, dim3(BH, 32, 2), dim3(256), 0, stream,
                     qbf, kbf, cs);
  hipLaunchKernelGGL(k_cwreduce, dim3(BHS / 256), dim3(256), 0, stream, cs, lcw);
  hipLaunchKernelGGL(k_attn_mfma, dim3(BH, 32, 2), dim3(256), 0, stream,
                     qbf, kbf, vtb, lcw, po0, po1, prp);
  hipLaunchKernelGGL(k_combine, dim3(SS / 64, BH), dim3(256), 0, stream,
                     po0, po1, prp, aobf);
  hipLaunchKernelGGL(k_gemm_out_mfma, dim3(768), dim3(256), 0, stream,
                     aobf, wt + 3 * WSZ, bo, hidden, y);
  hipLaunchKernelGGL(k_ln, dim3(MM), dim3(256), 0, stream, y, lng, lnb, out);
}